// Round 8
// baseline (131.047 us; speedup 1.0000x reference)
//
#include <hip/hip_runtime.h>
#include <math.h>

#define D_MODEL 1024
#define HEAD 64
#define SEQ 2048
#define BATCH 4

typedef _Float16 f16x4 __attribute__((ext_vector_type(4)));
typedef _Float16 f16x8 __attribute__((ext_vector_type(8)));
typedef float f32x4 __attribute__((ext_vector_type(4)));

// ---------------- prepass: wT[192][1024] fp16 from wq/wk/wv fp32 [1024][64] ---
__global__ __launch_bounds__(256) void prep_w(
    const float* __restrict__ wq, const float* __restrict__ wk,
    const float* __restrict__ wv, _Float16* __restrict__ wT)
{
    const float* w = (blockIdx.y == 0) ? wq : (blockIdx.y == 1) ? wk : wv;
    const int kbase = blockIdx.x * 64;
    __shared__ float t[64][65];
    const int tid = threadIdx.x;
    #pragma unroll
    for (int i = 0; i < 16; i++) {
        int idx = tid + i * 256;
        int kk = idx >> 6, c = idx & 63;
        t[kk][c] = w[(size_t)(kbase + kk) * 64 + c];
    }
    __syncthreads();
    #pragma unroll
    for (int i = 0; i < 16; i++) {
        int idx = tid + i * 256;
        int c = idx >> 6, kk = idx & 63;
        wT[(size_t)(blockIdx.y * 64 + c) * 1024 + kbase + kk] = (_Float16)t[kk][c];
    }
}

// ---------------- fused QKV projection: ring-4 LDS relay, fp16 MFMA -----------
// grid 512 x 768 thr (12 waves, 2 blocks/CU). Block: 16 rows x 192 fused cols;
// wave w owns cols [16w,16w+16). x chunk loads issued 4 ahead in a register
// ring (full unroll, constant ring indices); ds_write of chunk c+1 lands ~3
// iterations after its load was issued -> deep vmcnt cover. wT per-chunk from
// L2. Single barrier per chunk, double LDS buffer.
__global__ __launch_bounds__(768, 6) void proj_kernel(
    const float* __restrict__ x, const _Float16* __restrict__ wT,
    const float* __restrict__ bq, const float* __restrict__ bk2,
    const float* __restrict__ bv,
    _Float16* __restrict__ q, _Float16* __restrict__ k, _Float16* __restrict__ vT)
{
    const int tid = threadIdx.x;
    const int wave = tid >> 6;          // 0..11
    const int lane = tid & 63;
    const int l16 = lane & 15;
    const int quad = lane >> 4;
    const int row0 = blockIdx.x * 16;

    __shared__ __align__(16) _Float16 Xs[2][16][136];   // pitch 272B

    const int srow = tid >> 5;          // 0..15 (tid<512)
    const int sc4 = tid & 31;
    const float4* xg = reinterpret_cast<const float4*>(x)
                     + (size_t)(row0 + srow) * (D_MODEL / 4) + sc4;

    const _Float16* wp = wT + (size_t)(wave * 16 + l16) * D_MODEL + quad * 8;

    // prologue: load chunks 0..3 into the ring; publish chunk 0 into buf 0
    float4 xr[4];
    if (tid < 512) {
        xr[0] = xg[0];
        xr[1] = xg[32];
        xr[2] = xg[64];
        xr[3] = xg[96];
        f16x4 h;
        h[0] = (_Float16)xr[0].x; h[1] = (_Float16)xr[0].y;
        h[2] = (_Float16)xr[0].z; h[3] = (_Float16)xr[0].w;
        *(f16x4*)&Xs[0][srow][sc4 * 4] = h;
    }

    f32x4 acc = (f32x4){0.f, 0.f, 0.f, 0.f};

    #pragma unroll
    for (int c = 0; c < 8; c++) {
        __syncthreads();                 // publish buf[c&1]; order buf reuse
        // wT loads for THIS chunk (L2-hot)
        f16x8 bw0 = *(const f16x8*)(wp + c * 128);
        f16x8 bw1 = *(const f16x8*)(wp + c * 128 + 32);
        f16x8 bw2 = *(const f16x8*)(wp + c * 128 + 64);
        f16x8 bw3 = *(const f16x8*)(wp + c * 128 + 96);
        if (tid < 512) {
            // refill ring slot (c&3) with chunk c+4 (issued 4 iters ahead)
            if (c + 4 < 8) xr[c & 3] = xg[(c + 4) * 32];
            // publish chunk c+1 (loaded >=3 iters ago) into the other buffer
            if (c < 7) {
                float4 f = xr[(c + 1) & 3];
                f16x4 h;
                h[0] = (_Float16)f.x; h[1] = (_Float16)f.y;
                h[2] = (_Float16)f.z; h[3] = (_Float16)f.w;
                *(f16x4*)&Xs[(c + 1) & 1][srow][sc4 * 4] = h;
            }
        }
        const int bsel = c & 1;
        f16x8 aX0 = *(const f16x8*)&Xs[bsel][l16][0 * 32 + quad * 8];
        f16x8 aX1 = *(const f16x8*)&Xs[bsel][l16][1 * 32 + quad * 8];
        f16x8 aX2 = *(const f16x8*)&Xs[bsel][l16][2 * 32 + quad * 8];
        f16x8 aX3 = *(const f16x8*)&Xs[bsel][l16][3 * 32 + quad * 8];
        acc = __builtin_amdgcn_mfma_f32_16x16x32_f16(aX0, bw0, acc, 0, 0, 0);
        acc = __builtin_amdgcn_mfma_f32_16x16x32_f16(aX1, bw1, acc, 0, 0, 0);
        acc = __builtin_amdgcn_mfma_f32_16x16x32_f16(aX2, bw2, acc, 0, 0, 0);
        acc = __builtin_amdgcn_mfma_f32_16x16x32_f16(aX3, bw3, acc, 0, 0, 0);
    }

    // epilogue: C/D layout col=l16, row=quad*4+r; tensor choice wave-uniform
    const int g = wave * 16 + l16;       // fused col 0..191
    const int batch = row0 / SEQ;
    const int rbase = row0 + quad * 4;
    if (g < 64) {
        float bias = bq[g];
        #pragma unroll
        for (int r = 0; r < 4; r++)
            q[(size_t)(rbase + r) * HEAD + g] = (_Float16)((acc[r] + bias) * 0.125f);
    } else if (g < 128) {
        float bias = bk2[g - 64];
        #pragma unroll
        for (int r = 0; r < 4; r++)
            k[(size_t)(rbase + r) * HEAD + (g - 64)] = (_Float16)(acc[r] + bias);
    } else {
        float bias = bv[g - 128];
        f16x4 pk;
        #pragma unroll
        for (int r = 0; r < 4; r++) pk[r] = (_Float16)(acc[r] + bias);
        const int seq0 = row0 - batch * SEQ + quad * 4;
        *(f16x4*)(vT + (size_t)(batch * HEAD + (g - 128)) * SEQ + seq0) = pk;
    }
}

// ---------------- flash attention: zero-LDS loop, direct L2 reads -------------
// grid (64,4) x 512 thr. Block: 32 queries x all keys; wave w owns key strips
// {w*16 + 128c}. No LDS/barriers in the loop (no cross-wave reuse exists);
// K (b128) and V (b64 x4) read straight from L2 with a one-chunk register
// relay (#pragma unroll 1 pins the schedule). S^T via x32 MFMA; exp(S^T)
// C-layout == B-layout of P^T feeds O^T += V^T P^T (x16). No-max softmax =>
// wave partials additive; merged once via LDS at the end.
__global__ __launch_bounds__(512, 4) void attn_kernel(
    const _Float16* __restrict__ q, const _Float16* __restrict__ k,
    const _Float16* __restrict__ vT, float* __restrict__ out)
{
    const int tid = threadIdx.x;
    const int wave = tid >> 6;
    const int lane = tid & 63;
    const int l16 = lane & 15;
    const int quad = lane >> 4;
    const int b = blockIdx.y;
    const int q0 = blockIdx.x * 32;

    __shared__ float Oall[8][32][68];   // 69632 B
    __shared__ float Lall[8][32];

    // Q^T B-frags: bQ[qt][ks]: n=query=qt*16+l16, k=d=ks*32+quad*8
    f16x8 bQ[2][2];
    #pragma unroll
    for (int qt = 0; qt < 2; qt++) {
        const _Float16* qp = q + (size_t)(b * SEQ + q0 + qt * 16 + l16) * HEAD + quad * 8;
        bQ[qt][0] = *(const f16x8*)qp;
        bQ[qt][1] = *(const f16x8*)(qp + 32);
    }

    f32x4 O[2][4];
    #pragma unroll
    for (int qt = 0; qt < 2; qt++)
        #pragma unroll
        for (int dt = 0; dt < 4; dt++) O[qt][dt] = (f32x4){0.f, 0.f, 0.f, 0.f};
    float lp0 = 0.f, lp1 = 0.f;

    // per-wave strip base pointers
    const _Float16* kg = k + (size_t)b * SEQ * HEAD
                       + (size_t)(wave * 16 + l16) * HEAD + quad * 8;
    const _Float16* vg = vT + (size_t)b * HEAD * SEQ
                       + (size_t)l16 * SEQ + wave * 16 + quad * 4;

    // prologue: chunk 0 into current regs
    f16x8 ck0 = *(const f16x8*)kg;
    f16x8 ck1 = *(const f16x8*)(kg + 32);
    f16x4 cv0 = *(const f16x4*)(vg);
    f16x4 cv1 = *(const f16x4*)(vg + 16 * SEQ);
    f16x4 cv2 = *(const f16x4*)(vg + 32 * SEQ);
    f16x4 cv3 = *(const f16x4*)(vg + 48 * SEQ);

    #pragma unroll 1
    for (int c = 0; c < 16; c++) {
        f16x8 nk0, nk1;
        f16x4 nv0, nv1, nv2, nv3;
        if (c < 15) {    // issue next chunk's loads before computing current
            const _Float16* kp = kg + (size_t)(c + 1) * 128 * HEAD;
            nk0 = *(const f16x8*)kp;
            nk1 = *(const f16x8*)(kp + 32);
            const _Float16* vp = vg + (c + 1) * 128;
            nv0 = *(const f16x4*)(vp);
            nv1 = *(const f16x4*)(vp + 16 * SEQ);
            nv2 = *(const f16x4*)(vp + 32 * SEQ);
            nv3 = *(const f16x4*)(vp + 48 * SEQ);
        }
        // S^T per q-tile, then exp -> P^T B-frags (C==B layout identity)
        f16x4 bP[2];
        #pragma unroll
        for (int qt = 0; qt < 2; qt++) {
            f32x4 st = __builtin_amdgcn_mfma_f32_16x16x32_f16(ck0, bQ[qt][0], (f32x4){0.f, 0.f, 0.f, 0.f}, 0, 0, 0);
            st = __builtin_amdgcn_mfma_f32_16x16x32_f16(ck1, bQ[qt][1], st, 0, 0, 0);
            float p0 = __expf(st[0]);
            float p1 = __expf(st[1]);
            float p2 = __expf(st[2]);
            float p3 = __expf(st[3]);
            if (qt == 0) lp0 += (p0 + p1) + (p2 + p3);
            else         lp1 += (p0 + p1) + (p2 + p3);
            f16x4 bp;
            bp[0] = (_Float16)p0; bp[1] = (_Float16)p1;
            bp[2] = (_Float16)p2; bp[3] = (_Float16)p3;
            bP[qt] = bp;
        }
        // O^T += V^T P^T : aV shared by both q-tiles
        #pragma unroll
        for (int qt = 0; qt < 2; qt++) {
            O[qt][0] = __builtin_amdgcn_mfma_f32_16x16x16f16(cv0, bP[qt], O[qt][0], 0, 0, 0);
            O[qt][1] = __builtin_amdgcn_mfma_f32_16x16x16f16(cv1, bP[qt], O[qt][1], 0, 0, 0);
            O[qt][2] = __builtin_amdgcn_mfma_f32_16x16x16f16(cv2, bP[qt], O[qt][2], 0, 0, 0);
            O[qt][3] = __builtin_amdgcn_mfma_f32_16x16x16f16(cv3, bP[qt], O[qt][3], 0, 0, 0);
        }
        if (c < 15) {
            ck0 = nk0; ck1 = nk1;
            cv0 = nv0; cv1 = nv1; cv2 = nv2; cv3 = nv3;
        }
    }

    // reduce l across quads (lane holds partial for query qt*16+l16)
    lp0 += __shfl_xor(lp0, 16); lp0 += __shfl_xor(lp0, 32);
    lp1 += __shfl_xor(lp1, 16); lp1 += __shfl_xor(lp1, 32);
    if (lane < 16) {
        Lall[wave][l16] = lp0;
        Lall[wave][16 + l16] = lp1;
    }
    // O^T C-layout: row = d-in-tile = quad*4+r, col = query = l16
    #pragma unroll
    for (int qt = 0; qt < 2; qt++)
        #pragma unroll
        for (int dt = 0; dt < 4; dt++)
            #pragma unroll
            for (int r = 0; r < 4; r++)
                Oall[wave][qt * 16 + l16][dt * 16 + quad * 4 + r] = O[qt][dt][r];
    __syncthreads();

    // merge 8 additive wave partials: 512 thr x 4 outputs (32q x 64d)
    {
        int qi = tid >> 4;               // 0..31
        int dg = tid & 15;               // 4 d-values each
        float L = 0.f;
        float o[4] = {0.f, 0.f, 0.f, 0.f};
        #pragma unroll
        for (int w = 0; w < 8; w++) {
            L += Lall[w][qi];
            #pragma unroll
            for (int j = 0; j < 4; j++) o[j] += Oall[w][qi][dg * 4 + j];
        }
        float inv = 1.f / L;
        float4 res;
        res.x = o[0] * inv; res.y = o[1] * inv;
        res.z = o[2] * inv; res.w = o[3] * inv;
        *(float4*)(out + (size_t)(b * SEQ + q0 + qi) * HEAD + dg * 4) = res;
    }
}

extern "C" void kernel_launch(void* const* d_in, const int* in_sizes, int n_in,
                              void* d_out, int out_size, void* d_ws, size_t ws_size,
                              hipStream_t stream) {
    const float* x  = (const float*)d_in[0];
    const float* wq = (const float*)d_in[1];
    const float* bq = (const float*)d_in[2];
    const float* wk = (const float*)d_in[3];
    const float* bk = (const float*)d_in[4];
    const float* wv = (const float*)d_in[5];
    const float* bv = (const float*)d_in[6];
    float* out = (float*)d_out;

    const size_t proj_elems = (size_t)BATCH * SEQ * HEAD;  // 524288
    _Float16* qh = (_Float16*)d_ws;
    _Float16* kh = qh + proj_elems;
    _Float16* vT = kh + proj_elems;
    _Float16* wT = vT + proj_elems;   // 192*1024 elems

    prep_w<<<dim3(16, 3), 256, 0, stream>>>(wq, wk, wv, wT);
    proj_kernel<<<dim3(BATCH * SEQ / 16), 768, 0, stream>>>(x, wT, bq, bk, bv, qh, kh, vT);
    attn_kernel<<<dim3(SEQ / 32, BATCH), 512, 0, stream>>>(qh, kh, vT, out);
}